// Round 9
// baseline (5047.992 us; speedup 1.0000x reference)
//
#include <hip/hip_runtime.h>
#include <hip/hip_bf16.h>
#include <hip/hip_fp16.h>

#define HW 128
#define NPX 16384
#define CC 256

// fp8 e5m2: top byte of fp16, round-to-nearest on encode
struct F8 { unsigned char b; };
__device__ __forceinline__ unsigned char enc8(float v) {
    unsigned short u = __half_as_ushort(__float2half(v));
    unsigned short s = u & 0x8000, mag = u & 0x7FFF;
    mag = (unsigned short)(mag + 0x0080);
    return (unsigned char)((unsigned short)(s | mag) >> 8);
}
__device__ __forceinline__ float dec8(F8 v) {
    return __half2float(__ushort_as_half((unsigned short)(v.b) << 8));
}
__device__ __forceinline__ float ldg_(const float* p) { return *p; }
__device__ __forceinline__ float ldg_(const F8* p)    { return dec8(*p); }

// ORConv rotation: c_ROT[r][k] = RING[(INV[k]-r)&7], RING={0,1,2,5,8,7,6,3}.
__constant__ int c_ROT9[8][9] = {
    {0,1,2,3,4,5,6,7,8},
    {3,0,1,6,4,2,7,8,5},
    {6,3,0,7,4,1,8,5,2},
    {7,6,3,8,4,0,5,2,1},
    {8,7,6,5,4,3,2,1,0},
    {5,8,7,2,4,6,1,0,3},
    {2,5,8,1,4,7,0,3,6},
    {1,2,5,0,4,8,3,6,7},
};

// decode helper: fam_bbox fp32 [5,NPX] + px -> refined rotated box (fp32)
__device__ __forceinline__ void v9_decode_px(
    const float* bbox, int px, float s,
    float& gx, float& gy, float& gw, float& gh, float& ga)
{
    int y = px >> 7, x = px & 127;
    float ax = x * s + 3.5f, ay = y * s + 3.5f;
    float dx = bbox[0 * NPX + px];
    float dy = bbox[1 * NPX + px];
    float dw = bbox[2 * NPX + px];
    float dh = bbox[3 * NPX + px];
    float dt = bbox[4 * NPX + px];
    const float maxr = 13.815510558f;
    dw = fminf(fmaxf(dw, -maxr), maxr);
    dh = fminf(fmaxf(dh, -maxr), maxr);
    // anchor angle = 0: cos=1, sin=0
    gx = dx * 32.f + ax;
    gy = dy * 32.f + ay;
    gw = 32.f * expf(dw);
    gh = 32.f * expf(dh);
    const float PI = 3.14159265358979323846f;
    float m = fmodf(dt + PI * 0.25f, PI);
    if (m < 0.f) m += PI;
    ga = m - PI * 0.25f;
}

// ---------------------------------------------------------------------------
// 3x3 conv pad=1 -> fp8. Block 256 = 16 oc-grp(x4) x 16 x-grp(x8). Grid (128,4).
// ---------------------------------------------------------------------------
template <typename TIN, int RELU, int ORCONV>
__global__ __launch_bounds__(256) void v9_conv3x3(
    const TIN* __restrict__ in, const float* __restrict__ w,
    const float* __restrict__ bias, F8* __restrict__ out, int Cin)
{
    const int y   = blockIdx.x;
    const int ocb = blockIdx.y * 64;
    const int tid = threadIdx.x;
    const int xg  = tid & 15;
    const int og  = tid >> 4;
    const int x0  = xg * 8;
    const int oc0 = ocb + og * 4;

    __shared__ float srow[3][132];
    float acc[4][8];
#pragma unroll
    for (int i = 0; i < 4; ++i)
#pragma unroll
        for (int j = 0; j < 8; ++j) acc[i][j] = 0.f;

    for (int ci = 0; ci < Cin; ++ci) {
        __syncthreads();
        const TIN* inp = in + (size_t)ci * NPX;
        for (int t = tid; t < 3 * 130; t += 256) {
            int r = t / 130, c = t - r * 130;
            int yy = y - 1 + r, xx = c - 1;
            float v = 0.f;
            if (yy >= 0 && yy < HW && xx >= 0 && xx < HW) v = ldg_(inp + yy * HW + xx);
            srow[r][c] = v;
        }
        __syncthreads();

        float wv[4][9];
#pragma unroll
        for (int i = 0; i < 4; ++i) {
            if (ORCONV) {
                int oc = oc0 + i;
                const float* wp = w + ((size_t)(oc >> 3) * Cin + ci) * 9;
                const int* rot = c_ROT9[oc & 7];
#pragma unroll
                for (int k = 0; k < 9; ++k) wv[i][k] = wp[rot[k]];
            } else {
                const float* wp = w + ((size_t)(oc0 + i) * Cin + ci) * 9;
#pragma unroll
                for (int k = 0; k < 9; ++k) wv[i][k] = wp[k];
            }
        }
#pragma unroll
        for (int r = 0; r < 3; ++r) {
            float iv[10];
#pragma unroll
            for (int c = 0; c < 10; ++c) iv[c] = srow[r][x0 + c];
#pragma unroll
            for (int dxk = 0; dxk < 3; ++dxk)
#pragma unroll
                for (int i = 0; i < 4; ++i)
#pragma unroll
                    for (int j = 0; j < 8; ++j)
                        acc[i][j] += iv[j + dxk] * wv[i][r * 3 + dxk];
        }
    }
#pragma unroll
    for (int i = 0; i < 4; ++i) {
        float b = ORCONV ? bias[(oc0 + i) >> 3] : bias[oc0 + i];
#pragma unroll
        for (int j = 0; j < 8; ++j) {
            float v = acc[i][j] + b;
            if (RELU) v = fmaxf(v, 0.f);
            out[(size_t)(oc0 + i) * NPX + y * HW + x0 + j].b = enc8(v);
        }
    }
}

// 1x1 head: fp8 in [256,NPX] -> fp32 out [Cout,NPX]
__global__ __launch_bounds__(256) void v9_head1x1(
    const F8* __restrict__ in, const float* __restrict__ w,
    const float* __restrict__ bias, float* __restrict__ out, int Cout)
{
    int g = blockIdx.x * 256 + threadIdx.x;
    if (g >= Cout * NPX) return;
    int px = g & (NPX - 1);
    int oc = g >> 14;
    float acc = bias[oc];
    const float* wp = w + (size_t)oc * CC;
    for (int ci = 0; ci < CC; ++ci)
        acc += dec8(in[(size_t)ci * NPX + px]) * wp[ci];
    out[g] = acc;
}

// 3x3 head: fp8 in -> fp32 out, pad=1, no relu
__global__ __launch_bounds__(256) void v9_head3x3(
    const F8* __restrict__ in, const float* __restrict__ w,
    const float* __restrict__ bias, float* __restrict__ out, int Cout)
{
    int g = blockIdx.x * 256 + threadIdx.x;
    if (g >= Cout * NPX) return;
    int px = g & (NPX - 1);
    int oc = g >> 14;
    int y = px >> 7, x = px & 127;
    float acc = bias[oc];
    for (int ci = 0; ci < CC; ++ci) {
        const F8* ip = in + (size_t)ci * NPX;
        const float* wp = w + ((size_t)oc * CC + ci) * 9;
#pragma unroll
        for (int dy = 0; dy < 3; ++dy) {
            int yy = y + dy - 1;
            if (yy < 0 || yy >= HW) continue;
#pragma unroll
            for (int dxk = 0; dxk < 3; ++dxk) {
                int xx = x + dxk - 1;
                if (xx < 0 || xx >= HW) continue;
                acc += dec8(ip[yy * HW + xx]) * wp[dy * 3 + dxk];
            }
        }
    }
    out[g] = acc;
}

// anchors + refine decode -> fp32 d_out only
__global__ __launch_bounds__(256) void v9_decode(
    const float* __restrict__ bbox, float* __restrict__ anchors_out,
    float* __restrict__ refine_out, const int* __restrict__ stride_p)
{
    int px = blockIdx.x * 256 + threadIdx.x;
    if (px >= NPX) return;
    float s = (float)(*stride_p);
    int y = px >> 7, x = px & 127;
    anchors_out[px * 5 + 0] = x * s + 3.5f;
    anchors_out[px * 5 + 1] = y * s + 3.5f;
    anchors_out[px * 5 + 2] = 32.f;
    anchors_out[px * 5 + 3] = 32.f;
    anchors_out[px * 5 + 4] = 0.f;

    float gx, gy, gw, gh, ga;
    v9_decode_px(bbox, px, s, gx, gy, gw, gh, ga);
    refine_out[px * 5 + 0] = gx;
    refine_out[px * 5 + 1] = gy;
    refine_out[px * 5 + 2] = gw;
    refine_out[px * 5 + 3] = gh;
    refine_out[px * 5 + 4] = ga;
}

// align conv: coords derived in-kernel from fam_bbox (fp32). feats fp32 -> fp8.
__global__ __launch_bounds__(256) void v9_align(
    const float* __restrict__ in, const float* __restrict__ bbox,
    const float* __restrict__ w, const float* __restrict__ bias,
    const int* __restrict__ stride_p, F8* __restrict__ out)
{
    const int y   = blockIdx.x;
    const int ocb = blockIdx.y * 64;
    const int tid = threadIdx.x;
    const int xg  = tid & 15;
    const int og  = tid >> 4;
    const int x0  = xg * 8;
    const int oc0 = ocb + og * 4;

    __shared__ float smp[9][128];
    __shared__ int   s_ix[1152], s_iy[1152];
    __shared__ float s_wx1[1152], s_wy1[1152];

    const float s = (float)(*stride_p);
    for (int t = tid; t < 1152; t += 256) {
        int k = t >> 7, xx = t & 127;
        int px = y * HW + xx;
        float gx, gy, gw, gh, ga;
        v9_decode_px(bbox, px, s, gx, gy, gw, gh, ga);
        float axc = gx / s, ayc = gy / s;
        float aw3 = gw / (s * 3.f), ah3 = gh / (s * 3.f);
        float cs = cosf(ga), sn = sinf(ga);
        float kx = (float)(k % 3 - 1), ky = (float)(k / 3 - 1);
        float ddx = aw3 * kx, ddy = ah3 * ky;
        float xf = cs * ddx - sn * ddy + axc;
        float yf = sn * ddx + cs * ddy + ayc;
        float fx = floorf(xf), fy = floorf(yf);
        s_ix[t]  = (int)fx;
        s_iy[t]  = (int)fy;
        s_wx1[t] = xf - fx;
        s_wy1[t] = yf - fy;
    }

    float acc[4][8];
#pragma unroll
    for (int i = 0; i < 4; ++i)
#pragma unroll
        for (int j = 0; j < 8; ++j) acc[i][j] = 0.f;

    for (int ci = 0; ci < CC; ++ci) {
        __syncthreads();
        const float* ip = in + (size_t)ci * NPX;
        for (int t = tid; t < 1152; t += 256) {
            int ix = s_ix[t], iy = s_iy[t];
            float wx1 = s_wx1[t], wx0 = 1.f - wx1;
            float wy1 = s_wy1[t], wy0 = 1.f - wy1;
            float v = 0.f;
            bool xv0 = (ix >= 0) && (ix < HW);
            bool xv1 = (ix + 1 >= 0) && (ix + 1 < HW);
            bool yv0 = (iy >= 0) && (iy < HW);
            bool yv1 = (iy + 1 >= 0) && (iy + 1 < HW);
            if (yv0 && xv0) v += ip[iy * HW + ix] * wy0 * wx0;
            if (yv0 && xv1) v += ip[iy * HW + ix + 1] * wy0 * wx1;
            if (yv1 && xv0) v += ip[(iy + 1) * HW + ix] * wy1 * wx0;
            if (yv1 && xv1) v += ip[(iy + 1) * HW + ix + 1] * wy1 * wx1;
            smp[t >> 7][t & 127] = v;
        }
        __syncthreads();

        float wv[4][9];
#pragma unroll
        for (int i = 0; i < 4; ++i) {
            const float* wp = w + ((size_t)(oc0 + i) * CC + ci) * 9;
#pragma unroll
            for (int k = 0; k < 9; ++k) wv[i][k] = wp[k];
        }
#pragma unroll
        for (int k = 0; k < 9; ++k) {
            float iv[8];
#pragma unroll
            for (int j = 0; j < 8; ++j) iv[j] = smp[k][x0 + j];
#pragma unroll
            for (int i = 0; i < 4; ++i)
#pragma unroll
                for (int j = 0; j < 8; ++j)
                    acc[i][j] += iv[j] * wv[i][k];
        }
    }
#pragma unroll
    for (int i = 0; i < 4; ++i) {
        float b = bias[oc0 + i];
#pragma unroll
        for (int j = 0; j < 8; ++j)
            out[(size_t)(oc0 + i) * NPX + y * HW + x0 + j].b =
                enc8(fmaxf(acc[i][j] + b, 0.f));
    }
}

// rotation-invariant max pool: fp8 [256,NPX] -> fp8 [32,NPX]
__global__ __launch_bounds__(256) void v9_pool(
    const F8* __restrict__ orf, F8* __restrict__ pooled)
{
    int g = blockIdx.x * 256 + threadIdx.x;
    if (g >= 32 * NPX) return;
    int px = g & (NPX - 1);
    int c  = g >> 14;
    float m = -3.4e38f;
#pragma unroll
    for (int r = 0; r < 8; ++r)
        m = fmaxf(m, dec8(orf[(size_t)(c * 8 + r) * NPX + px]));
    pooled[g].b = enc8(m);
}

// ---------------------------------------------------------------------------
extern "C" void kernel_launch(void* const* d_in, const int* in_sizes, int n_in,
                              void* d_out, int out_size, void* d_ws, size_t ws_size,
                              hipStream_t stream)
{
    const float* feats = (const float*)d_in[0];
    const float* frw0 = (const float*)d_in[1];  const float* frb0 = (const float*)d_in[2];
    const float* frw1 = (const float*)d_in[3];  const float* frb1 = (const float*)d_in[4];
    const float* frhw = (const float*)d_in[5];  const float* frhb = (const float*)d_in[6];
    const float* fcw0 = (const float*)d_in[7];  const float* fcb0 = (const float*)d_in[8];
    const float* fcw1 = (const float*)d_in[9];  const float* fcb1 = (const float*)d_in[10];
    const float* fchw = (const float*)d_in[11]; const float* fchb = (const float*)d_in[12];
    const float* alw  = (const float*)d_in[13]; const float* alb  = (const float*)d_in[14];
    const float* orw  = (const float*)d_in[15]; const float* orb  = (const float*)d_in[16];
    const float* drw0 = (const float*)d_in[17]; const float* drb0 = (const float*)d_in[18];
    const float* drw1 = (const float*)d_in[19]; const float* drb1 = (const float*)d_in[20];
    const float* drhw = (const float*)d_in[21]; const float* drhb = (const float*)d_in[22];
    const float* dcw0 = (const float*)d_in[23]; const float* dcb0 = (const float*)d_in[24];
    const float* dcw1 = (const float*)d_in[25]; const float* dcb1 = (const float*)d_in[26];
    const float* dchw = (const float*)d_in[27]; const float* dchb = (const float*)d_in[28];
    const int*  stride_p = (const int*)d_in[29];

    // d_out is FLOAT32 (reference output dtype) — proven by round-8 sentinel.
    float* out = (float*)d_out;
    float* o_fam_cls  = out;              // 15*16384
    float* o_fam_bbox = out + 245760;     // 5*16384
    float* o_odm_cls  = out + 327680;     // 15*16384
    float* o_odm_bbox = out + 573440;     // 5*16384
    float* o_anchors  = out + 655360;     // 16384*5
    float* o_refine   = out + 737280;     // 16384*5

    // d_ws: A fp8 4MiB, B fp8 4MiB, P fp8 512KiB = 8.5 MiB, guarded.
    const size_t NEED = 8912896;
    if (ws_size < NEED) return;  // diagnostic signature: zeros -> fail@4 @1020.0
    F8* A = (F8*)d_ws;
    F8* B = (F8*)((char*)d_ws + 4194304);
    F8* P = (F8*)((char*)d_ws + 8388608);

    dim3 blk(256);
    dim3 gconv(128, 4);

    // FAM reg
    v9_conv3x3<float, 1, 0><<<gconv, blk, 0, stream>>>(feats, frw0, frb0, A, 256);
    v9_conv3x3<F8,    1, 0><<<gconv, blk, 0, stream>>>(A, frw1, frb1, B, 256);
    v9_head1x1<<<dim3(5 * 64), blk, 0, stream>>>(B, frhw, frhb, o_fam_bbox, 5);
    // FAM cls
    v9_conv3x3<float, 1, 0><<<gconv, blk, 0, stream>>>(feats, fcw0, fcb0, A, 256);
    v9_conv3x3<F8,    1, 0><<<gconv, blk, 0, stream>>>(A, fcw1, fcb1, B, 256);
    v9_head1x1<<<dim3(15 * 64), blk, 0, stream>>>(B, fchw, fchb, o_fam_cls, 15);
    // anchors + refine
    v9_decode<<<dim3(64), blk, 0, stream>>>(o_fam_bbox, o_anchors, o_refine, stride_p);
    // align conv (coords in-kernel from fam_bbox) -> A
    v9_align<<<gconv, blk, 0, stream>>>(feats, o_fam_bbox, alw, alb, stride_p, A);
    // OR conv (rotation fused) -> B (= orf, no relu)
    v9_conv3x3<F8, 0, 1><<<gconv, blk, 0, stream>>>(A, orw, orb, B, 256);
    // pool -> P
    v9_pool<<<dim3(2048), blk, 0, stream>>>(B, P);
    // ODM reg: B -> A -> B -> head
    v9_conv3x3<F8, 1, 0><<<gconv, blk, 0, stream>>>(B, drw0, drb0, A, 256);
    v9_conv3x3<F8, 1, 0><<<gconv, blk, 0, stream>>>(A, drw1, drb1, B, 256);
    v9_head3x3<<<dim3(5 * 64), blk, 0, stream>>>(B, drhw, drhb, o_odm_bbox, 5);
    // ODM cls: P -> A (Cin=32) -> B -> head
    v9_conv3x3<F8, 1, 0><<<gconv, blk, 0, stream>>>(P, dcw0, dcb0, A, 32);
    v9_conv3x3<F8, 1, 0><<<gconv, blk, 0, stream>>>(A, dcw1, dcb1, B, 256);
    v9_head3x3<<<dim3(15 * 64), blk, 0, stream>>>(B, dchw, dchb, o_odm_cls, 15);
}

// Round 10
// 2224.420 us; speedup vs baseline: 2.2694x; 2.2694x over previous
//
#include <hip/hip_runtime.h>
#include <hip/hip_bf16.h>
#include <hip/hip_fp16.h>

#define HW 128
#define NPX 16384
#define CC 256

typedef short  bf16x8  __attribute__((ext_vector_type(8)));
typedef short  short4v __attribute__((ext_vector_type(4)));
typedef float  f32x4   __attribute__((ext_vector_type(4)));

// ---- scalar bf16 bit helpers (self-contained, RNE) ----
static __device__ __forceinline__ short f2bs(float v) {
    union { float f; unsigned u; } x; x.f = v;
    unsigned r = x.u + 0x7FFFu + ((x.u >> 16) & 1u);
    return (short)(r >> 16);
}
static __device__ __forceinline__ float bs2f(short s) {
    union { unsigned u; float f; } x; x.u = ((unsigned)(unsigned short)s) << 16;
    return x.f;
}

// fp8 e5m2 (v9 fallback path)
struct F8 { unsigned char b; };
__device__ __forceinline__ unsigned char enc8(float v) {
    unsigned short u = __half_as_ushort(__float2half(v));
    unsigned short s = u & 0x8000, mag = u & 0x7FFF;
    mag = (unsigned short)(mag + 0x0080);
    return (unsigned char)((unsigned short)(s | mag) >> 8);
}
__device__ __forceinline__ float dec8(F8 v) {
    return __half2float(__ushort_as_half((unsigned short)(v.b) << 8));
}
__device__ __forceinline__ float ldg_(const float* p) { return *p; }
__device__ __forceinline__ float ldg_(const F8* p)    { return dec8(*p); }

// ORConv rotation: c_ROT[r][k] = RING[(INV[k]-r)&7], RING={0,1,2,5,8,7,6,3}.
__constant__ int c_ROT9[8][9] = {
    {0,1,2,3,4,5,6,7,8},
    {3,0,1,6,4,2,7,8,5},
    {6,3,0,7,4,1,8,5,2},
    {7,6,3,8,4,0,5,2,1},
    {8,7,6,5,4,3,2,1,0},
    {5,8,7,2,4,6,1,0,3},
    {2,5,8,1,4,7,0,3,6},
    {1,2,5,0,4,8,3,6,7},
};

// decode helper: fam_bbox fp32 [5,NPX] + px -> refined rotated box (fp32)
__device__ __forceinline__ void v9_decode_px(
    const float* bbox, int px, float s,
    float& gx, float& gy, float& gw, float& gh, float& ga)
{
    int y = px >> 7, x = px & 127;
    float ax = x * s + 3.5f, ay = y * s + 3.5f;
    float dx = bbox[0 * NPX + px];
    float dy = bbox[1 * NPX + px];
    float dw = bbox[2 * NPX + px];
    float dh = bbox[3 * NPX + px];
    float dt = bbox[4 * NPX + px];
    const float maxr = 13.815510558f;
    dw = fminf(fmaxf(dw, -maxr), maxr);
    dh = fminf(fmaxf(dh, -maxr), maxr);
    gx = dx * 32.f + ax;
    gy = dy * 32.f + ay;
    gw = 32.f * expf(dw);
    gh = 32.f * expf(dh);
    const float PI = 3.14159265358979323846f;
    float m = fmodf(dt + PI * 0.25f, PI);
    if (m < 0.f) m += PI;
    ga = m - PI * 0.25f;
}

// ===========================================================================
// ============================  V10 FAST PATH  ==============================
// Activations in [px][ci] bf16. MFMA 16x16x32 bf16 implicit-GEMM convs.
// ===========================================================================

// feats [256][16384] fp32 -> xt [16384][256] bf16 (LDS 32x32 tile transpose)
__global__ __launch_bounds__(256) void v10_transpose(
    const float* __restrict__ f, short* __restrict__ xt)
{
    __shared__ float tile[32][33];
    int px0 = blockIdx.x * 32, ci0 = blockIdx.y * 32;
    int tx = threadIdx.x & 31, ty = threadIdx.x >> 5;  // ty 0..7
#pragma unroll
    for (int i = 0; i < 4; ++i) {
        int ci = ty + i * 8;
        tile[ci][tx] = f[(size_t)(ci0 + ci) * NPX + px0 + tx];
    }
    __syncthreads();
#pragma unroll
    for (int i = 0; i < 4; ++i) {
        int pxr = ty + i * 8;
        xt[(size_t)(px0 + pxr) * 256 + ci0 + tx] = f2bs(tile[tx][pxr]);
    }
}

// weight prep -> wb[t][ocp][ci] bf16 (+ padded bias bb[ocp] fp32)
// mode 0: plain 3x3 [Cout][Cin][9]; 1: orconv [32][Cin][9] (rotation+bias rep);
// mode 2: 1x1 [Cout][Cin] (written into tap slot 4, others zero)
__global__ __launch_bounds__(256) void v10_prep(
    const float* __restrict__ w, const float* __restrict__ bias,
    short* __restrict__ wb, float* __restrict__ bb,
    int Cout, int Cin, int OCP, int mode)
{
    int g = blockIdx.x * 256 + threadIdx.x;
    if (g < OCP) bb[g] = (g < Cout) ? ((mode == 1) ? bias[g >> 3] : bias[g]) : 0.f;
    int tot = 9 * OCP * Cin;
    if (g >= tot) return;
    int t   = g / (OCP * Cin);
    int rem = g - t * OCP * Cin;
    int oc  = rem / Cin;
    int ci  = rem - oc * Cin;
    float v = 0.f;
    if (oc < Cout) {
        if (mode == 0)      v = w[((size_t)oc * Cin + ci) * 9 + t];
        else if (mode == 1) { int o = oc >> 3, r = oc & 7;
                              v = w[((size_t)o * Cin + ci) * 9 + c_ROT9[r][t]]; }
        else if (t == 4)    v = w[(size_t)oc * Cin + ci];
    }
    wb[g] = f2bs(v);
}

// MFMA conv: in [px][CIN] bf16, wb [t][OCP][CIN] bf16.
// HEAD=0: out [px][256] bf16 (+bias, opt relu). HEAD=1: out fp32 [oc][NPX] (+bias).
// Grid (256, OCP/64): blockIdx.x = (row<<1)|xhalf. Block 256 = 4 waves.
template <int RELU, int HEAD, int ONLY1, int CIN>
__global__ __launch_bounds__(256) void v10_conv(
    const short* __restrict__ xin, const short* __restrict__ wb,
    const float* __restrict__ bb, void* __restrict__ outv, int CoutAct)
{
    const int OCP  = gridDim.y * 64;
    const int y    = blockIdx.x >> 1;
    const int xh   = (blockIdx.x & 1) * 64;
    const int ocb  = blockIdx.y * 64;
    const int tid  = threadIdx.x;
    const int wv   = tid >> 6;
    const int lane = tid & 63;
    const int quad = lane >> 4;
    const int l15  = lane & 15;
    const int ocw  = ocb + wv * 16;

    f32x4 acc[4];
#pragma unroll
    for (int p = 0; p < 4; ++p) acc[p] = (f32x4){0.f, 0.f, 0.f, 0.f};
    const bf16x8 zf = (bf16x8){0,0,0,0,0,0,0,0};

    for (int cib = 0; cib < CIN; cib += 32) {
#pragma unroll
        for (int t = (ONLY1 ? 4 : 0); t < (ONLY1 ? 5 : 9); ++t) {
            const int yy = y + t / 3 - 1;
            if (yy < 0 || yy >= HW) continue;
            const int dxk = t % 3 - 1;
            bf16x8 a = *(const bf16x8*)(wb +
                ((size_t)(t * OCP + ocw + l15) * CIN + cib + quad * 8));
#pragma unroll
            for (int p = 0; p < 4; ++p) {
                int col = xh + p * 16 + l15 + dxk;
                bf16x8 b = zf;
                if (col >= 0 && col < HW)
                    b = *(const bf16x8*)(xin +
                        ((size_t)(yy * HW + col) * CIN + cib + quad * 8));
                acc[p] = __builtin_amdgcn_mfma_f32_16x16x32_bf16(a, b, acc[p], 0, 0, 0);
            }
        }
    }
#pragma unroll
    for (int p = 0; p < 4; ++p) {
        const int px  = y * HW + xh + p * 16 + l15;
        const int ocq = ocw + quad * 4;
        if (HEAD) {
            float* o = (float*)outv;
#pragma unroll
            for (int r = 0; r < 4; ++r)
                if (ocq + r < CoutAct)
                    o[(size_t)(ocq + r) * NPX + px] = acc[p][r] + bb[ocq + r];
        } else {
            short4v s4;
#pragma unroll
            for (int r = 0; r < 4; ++r) {
                float v = acc[p][r] + bb[ocq + r];
                if (RELU) v = fmaxf(v, 0.f);
                s4[r] = f2bs(v);
            }
            *(short4v*)((short*)outv + (size_t)px * 256 + ocq) = s4;
        }
    }
}

// MFMA align conv: coords once in LDS, bilinear tile S per (tap,cib), MFMA GEMM.
// Grid (128, 4). in xt [px][256] bf16, out [px][256] bf16 relu.
__global__ __launch_bounds__(256) void v10_align(
    const short* __restrict__ xt, const float* __restrict__ bbox,
    const short* __restrict__ wb, const float* __restrict__ bb,
    const int* __restrict__ stride_p, short* __restrict__ outa)
{
    const int y    = blockIdx.x;
    const int ocb  = blockIdx.y * 64;
    const int tid  = threadIdx.x;
    const int wv   = tid >> 6, lane = tid & 63, quad = lane >> 4, l15 = lane & 15;
    const int ocw  = ocb + wv * 16;

    __shared__ int   s_ix[1152], s_iy[1152];
    __shared__ float s_w00[1152], s_w01[1152], s_w10[1152], s_w11[1152];
    __shared__ short S[128][40];  // pad 40: 16B-aligned rows, <=2-way banks (free)

    const float s = (float)(*stride_p);
    for (int e = tid; e < 1152; e += 256) {
        int k = e >> 7, xx = e & 127;
        int px = y * HW + xx;
        float gx, gy, gw, gh, ga;
        v9_decode_px(bbox, px, s, gx, gy, gw, gh, ga);
        float axc = gx / s, ayc = gy / s;
        float aw3 = gw / (3.f * s), ah3 = gh / (3.f * s);
        float cs = cosf(ga), sn = sinf(ga);
        float kx = (float)(k % 3 - 1), ky = (float)(k / 3 - 1);
        float ddx = aw3 * kx, ddy = ah3 * ky;
        float xf = cs * ddx - sn * ddy + axc;
        float yf = sn * ddx + cs * ddy + ayc;
        float fx = floorf(xf), fy = floorf(yf);
        int ix = (int)fx, iy = (int)fy;
        float wx1 = xf - fx, wx0 = 1.f - wx1;
        float wy1 = yf - fy, wy0 = 1.f - wy1;
        bool x0v = (ix >= 0) && (ix < HW), x1v = (ix + 1 >= 0) && (ix + 1 < HW);
        bool y0v = (iy >= 0) && (iy < HW), y1v = (iy + 1 >= 0) && (iy + 1 < HW);
        s_ix[e] = ix; s_iy[e] = iy;
        s_w00[e] = (y0v && x0v) ? wy0 * wx0 : 0.f;
        s_w01[e] = (y0v && x1v) ? wy0 * wx1 : 0.f;
        s_w10[e] = (y1v && x0v) ? wy1 * wx0 : 0.f;
        s_w11[e] = (y1v && x1v) ? wy1 * wx1 : 0.f;
    }

    f32x4 acc[8];
#pragma unroll
    for (int p = 0; p < 8; ++p) acc[p] = (f32x4){0.f, 0.f, 0.f, 0.f};

    const int spx = tid >> 1;          // 0..127
    const int sci = (tid & 1) * 16;    // 0 / 16

    for (int cib = 0; cib < 256; cib += 32) {
        for (int t = 0; t < 9; ++t) {
            __syncthreads();
            {
                int e = t * 128 + spx;
                int ix = s_ix[e], iy = s_iy[e];
                float w00 = s_w00[e], w01 = s_w01[e], w10 = s_w10[e], w11 = s_w11[e];
                int x0c = min(max(ix, 0), HW - 1), x1c = min(max(ix + 1, 0), HW - 1);
                int y0c = min(max(iy, 0), HW - 1), y1c = min(max(iy + 1, 0), HW - 1);
                const short* p00 = xt + ((size_t)(y0c * HW + x0c) * 256 + cib + sci);
                const short* p01 = xt + ((size_t)(y0c * HW + x1c) * 256 + cib + sci);
                const short* p10 = xt + ((size_t)(y1c * HW + x0c) * 256 + cib + sci);
                const short* p11 = xt + ((size_t)(y1c * HW + x1c) * 256 + cib + sci);
                bf16x8 a0 = *(const bf16x8*)p00, a1 = *(const bf16x8*)(p00 + 8);
                bf16x8 b0 = *(const bf16x8*)p01, b1 = *(const bf16x8*)(p01 + 8);
                bf16x8 c0 = *(const bf16x8*)p10, c1 = *(const bf16x8*)(p10 + 8);
                bf16x8 d0 = *(const bf16x8*)p11, d1 = *(const bf16x8*)(p11 + 8);
#pragma unroll
                for (int i = 0; i < 8; ++i) {
                    float v = w00 * bs2f(a0[i]) + w01 * bs2f(b0[i])
                            + w10 * bs2f(c0[i]) + w11 * bs2f(d0[i]);
                    S[spx][sci + i] = f2bs(v);
                }
#pragma unroll
                for (int i = 0; i < 8; ++i) {
                    float v = w00 * bs2f(a1[i]) + w01 * bs2f(b1[i])
                            + w10 * bs2f(c1[i]) + w11 * bs2f(d1[i]);
                    S[spx][sci + 8 + i] = f2bs(v);
                }
            }
            __syncthreads();
            bf16x8 a = *(const bf16x8*)(wb +
                ((size_t)(t * 256 + ocw + l15) * 256 + cib + quad * 8));
#pragma unroll
            for (int p = 0; p < 8; ++p) {
                bf16x8 b = *(const bf16x8*)(&S[p * 16 + l15][quad * 8]);
                acc[p] = __builtin_amdgcn_mfma_f32_16x16x32_bf16(a, b, acc[p], 0, 0, 0);
            }
        }
    }
#pragma unroll
    for (int p = 0; p < 8; ++p) {
        const int px  = y * HW + p * 16 + l15;
        const int ocq = ocw + quad * 4;
        short4v s4;
#pragma unroll
        for (int r = 0; r < 4; ++r)
            s4[r] = f2bs(fmaxf(acc[p][r] + bb[ocq + r], 0.f));
        *(short4v*)(outa + (size_t)px * 256 + ocq) = s4;
    }
}

// pool: T [px][256] bf16 -> P [px][32] bf16 (max over 8 consecutive oc)
__global__ __launch_bounds__(256) void v10_pool(
    const short* __restrict__ t1, short* __restrict__ p)
{
    int g = blockIdx.x * 256 + threadIdx.x;
    if (g >= 32 * NPX) return;
    int px = g >> 5, c = g & 31;
    const short* q = t1 + (size_t)px * 256 + c * 8;
    float m = bs2f(q[0]);
#pragma unroll
    for (int r = 1; r < 8; ++r) m = fmaxf(m, bs2f(q[r]));
    p[(size_t)px * 32 + c] = f2bs(m);
}

// anchors + refine decode -> fp32 d_out (shared by both paths)
__global__ __launch_bounds__(256) void v9_decode(
    const float* __restrict__ bbox, float* __restrict__ anchors_out,
    float* __restrict__ refine_out, const int* __restrict__ stride_p)
{
    int px = blockIdx.x * 256 + threadIdx.x;
    if (px >= NPX) return;
    float s = (float)(*stride_p);
    int y = px >> 7, x = px & 127;
    anchors_out[px * 5 + 0] = x * s + 3.5f;
    anchors_out[px * 5 + 1] = y * s + 3.5f;
    anchors_out[px * 5 + 2] = 32.f;
    anchors_out[px * 5 + 3] = 32.f;
    anchors_out[px * 5 + 4] = 0.f;
    float gx, gy, gw, gh, ga;
    v9_decode_px(bbox, px, s, gx, gy, gw, gh, ga);
    refine_out[px * 5 + 0] = gx;
    refine_out[px * 5 + 1] = gy;
    refine_out[px * 5 + 2] = gw;
    refine_out[px * 5 + 3] = gh;
    refine_out[px * 5 + 4] = ga;
}

// ===========================================================================
// ============  V9 FALLBACK (verbatim from passing round 9)  ================
// ===========================================================================
template <typename TIN, int RELU, int ORCONV>
__global__ __launch_bounds__(256) void v9_conv3x3(
    const TIN* __restrict__ in, const float* __restrict__ w,
    const float* __restrict__ bias, F8* __restrict__ out, int Cin)
{
    const int y   = blockIdx.x;
    const int ocb = blockIdx.y * 64;
    const int tid = threadIdx.x;
    const int xg  = tid & 15;
    const int og  = tid >> 4;
    const int x0  = xg * 8;
    const int oc0 = ocb + og * 4;

    __shared__ float srow[3][132];
    float acc[4][8];
#pragma unroll
    for (int i = 0; i < 4; ++i)
#pragma unroll
        for (int j = 0; j < 8; ++j) acc[i][j] = 0.f;

    for (int ci = 0; ci < Cin; ++ci) {
        __syncthreads();
        const TIN* inp = in + (size_t)ci * NPX;
        for (int t = tid; t < 3 * 130; t += 256) {
            int r = t / 130, c = t - r * 130;
            int yy = y - 1 + r, xx = c - 1;
            float v = 0.f;
            if (yy >= 0 && yy < HW && xx >= 0 && xx < HW) v = ldg_(inp + yy * HW + xx);
            srow[r][c] = v;
        }
        __syncthreads();
        float wv[4][9];
#pragma unroll
        for (int i = 0; i < 4; ++i) {
            if (ORCONV) {
                int oc = oc0 + i;
                const float* wp = w + ((size_t)(oc >> 3) * Cin + ci) * 9;
                const int* rot = c_ROT9[oc & 7];
#pragma unroll
                for (int k = 0; k < 9; ++k) wv[i][k] = wp[rot[k]];
            } else {
                const float* wp = w + ((size_t)(oc0 + i) * Cin + ci) * 9;
#pragma unroll
                for (int k = 0; k < 9; ++k) wv[i][k] = wp[k];
            }
        }
#pragma unroll
        for (int r = 0; r < 3; ++r) {
            float iv[10];
#pragma unroll
            for (int c = 0; c < 10; ++c) iv[c] = srow[r][x0 + c];
#pragma unroll
            for (int dxk = 0; dxk < 3; ++dxk)
#pragma unroll
                for (int i = 0; i < 4; ++i)
#pragma unroll
                    for (int j = 0; j < 8; ++j)
                        acc[i][j] += iv[j + dxk] * wv[i][r * 3 + dxk];
        }
    }
#pragma unroll
    for (int i = 0; i < 4; ++i) {
        float b = ORCONV ? bias[(oc0 + i) >> 3] : bias[oc0 + i];
#pragma unroll
        for (int j = 0; j < 8; ++j) {
            float v = acc[i][j] + b;
            if (RELU) v = fmaxf(v, 0.f);
            out[(size_t)(oc0 + i) * NPX + y * HW + x0 + j].b = enc8(v);
        }
    }
}

__global__ __launch_bounds__(256) void v9_head1x1(
    const F8* __restrict__ in, const float* __restrict__ w,
    const float* __restrict__ bias, float* __restrict__ out, int Cout)
{
    int g = blockIdx.x * 256 + threadIdx.x;
    if (g >= Cout * NPX) return;
    int px = g & (NPX - 1);
    int oc = g >> 14;
    float acc = bias[oc];
    const float* wp = w + (size_t)oc * CC;
    for (int ci = 0; ci < CC; ++ci)
        acc += dec8(in[(size_t)ci * NPX + px]) * wp[ci];
    out[g] = acc;
}

__global__ __launch_bounds__(256) void v9_head3x3(
    const F8* __restrict__ in, const float* __restrict__ w,
    const float* __restrict__ bias, float* __restrict__ out, int Cout)
{
    int g = blockIdx.x * 256 + threadIdx.x;
    if (g >= Cout * NPX) return;
    int px = g & (NPX - 1);
    int oc = g >> 14;
    int y = px >> 7, x = px & 127;
    float acc = bias[oc];
    for (int ci = 0; ci < CC; ++ci) {
        const F8* ip = in + (size_t)ci * NPX;
        const float* wp = w + ((size_t)oc * CC + ci) * 9;
#pragma unroll
        for (int dy = 0; dy < 3; ++dy) {
            int yy = y + dy - 1;
            if (yy < 0 || yy >= HW) continue;
#pragma unroll
            for (int dxk = 0; dxk < 3; ++dxk) {
                int xx = x + dxk - 1;
                if (xx < 0 || xx >= HW) continue;
                acc += dec8(ip[yy * HW + xx]) * wp[dy * 3 + dxk];
            }
        }
    }
    out[g] = acc;
}

__global__ __launch_bounds__(256) void v9_align(
    const float* __restrict__ in, const float* __restrict__ bbox,
    const float* __restrict__ w, const float* __restrict__ bias,
    const int* __restrict__ stride_p, F8* __restrict__ out)
{
    const int y   = blockIdx.x;
    const int ocb = blockIdx.y * 64;
    const int tid = threadIdx.x;
    const int xg  = tid & 15;
    const int og  = tid >> 4;
    const int x0  = xg * 8;
    const int oc0 = ocb + og * 4;

    __shared__ float smp[9][128];
    __shared__ int   s_ix[1152], s_iy[1152];
    __shared__ float s_wx1[1152], s_wy1[1152];

    const float s = (float)(*stride_p);
    for (int t = tid; t < 1152; t += 256) {
        int k = t >> 7, xx = t & 127;
        int px = y * HW + xx;
        float gx, gy, gw, gh, ga;
        v9_decode_px(bbox, px, s, gx, gy, gw, gh, ga);
        float axc = gx / s, ayc = gy / s;
        float aw3 = gw / (s * 3.f), ah3 = gh / (s * 3.f);
        float cs = cosf(ga), sn = sinf(ga);
        float kx = (float)(k % 3 - 1), ky = (float)(k / 3 - 1);
        float ddx = aw3 * kx, ddy = ah3 * ky;
        float xf = cs * ddx - sn * ddy + axc;
        float yf = sn * ddx + cs * ddy + ayc;
        float fx = floorf(xf), fy = floorf(yf);
        s_ix[t]  = (int)fx;
        s_iy[t]  = (int)fy;
        s_wx1[t] = xf - fx;
        s_wy1[t] = yf - fy;
    }

    float acc[4][8];
#pragma unroll
    for (int i = 0; i < 4; ++i)
#pragma unroll
        for (int j = 0; j < 8; ++j) acc[i][j] = 0.f;

    for (int ci = 0; ci < CC; ++ci) {
        __syncthreads();
        const float* ip = in + (size_t)ci * NPX;
        for (int t = tid; t < 1152; t += 256) {
            int ix = s_ix[t], iy = s_iy[t];
            float wx1 = s_wx1[t], wx0 = 1.f - wx1;
            float wy1 = s_wy1[t], wy0 = 1.f - wy1;
            float v = 0.f;
            bool xv0 = (ix >= 0) && (ix < HW);
            bool xv1 = (ix + 1 >= 0) && (ix + 1 < HW);
            bool yv0 = (iy >= 0) && (iy < HW);
            bool yv1 = (iy + 1 >= 0) && (iy + 1 < HW);
            if (yv0 && xv0) v += ip[iy * HW + ix] * wy0 * wx0;
            if (yv0 && xv1) v += ip[iy * HW + ix + 1] * wy0 * wx1;
            if (yv1 && xv0) v += ip[(iy + 1) * HW + ix] * wy1 * wx0;
            if (yv1 && xv1) v += ip[(iy + 1) * HW + ix + 1] * wy1 * wx1;
            smp[t >> 7][t & 127] = v;
        }
        __syncthreads();

        float wv[4][9];
#pragma unroll
        for (int i = 0; i < 4; ++i) {
            const float* wp = w + ((size_t)(oc0 + i) * CC + ci) * 9;
#pragma unroll
            for (int k = 0; k < 9; ++k) wv[i][k] = wp[k];
        }
#pragma unroll
        for (int k = 0; k < 9; ++k) {
            float iv[8];
#pragma unroll
            for (int j = 0; j < 8; ++j) iv[j] = smp[k][x0 + j];
#pragma unroll
            for (int i = 0; i < 4; ++i)
#pragma unroll
                for (int j = 0; j < 8; ++j)
                    acc[i][j] += iv[j] * wv[i][k];
        }
    }
#pragma unroll
    for (int i = 0; i < 4; ++i) {
        float b = bias[oc0 + i];
#pragma unroll
        for (int j = 0; j < 8; ++j)
            out[(size_t)(oc0 + i) * NPX + y * HW + x0 + j].b =
                enc8(fmaxf(acc[i][j] + b, 0.f));
    }
}

__global__ __launch_bounds__(256) void v9_pool(
    const F8* __restrict__ orf, F8* __restrict__ pooled)
{
    int g = blockIdx.x * 256 + threadIdx.x;
    if (g >= 32 * NPX) return;
    int px = g & (NPX - 1);
    int c  = g >> 14;
    float m = -3.4e38f;
#pragma unroll
    for (int r = 0; r < 8; ++r)
        m = fmaxf(m, dec8(orf[(size_t)(c * 8 + r) * NPX + px]));
    pooled[g].b = enc8(m);
}

// ===========================================================================
extern "C" void kernel_launch(void* const* d_in, const int* in_sizes, int n_in,
                              void* d_out, int out_size, void* d_ws, size_t ws_size,
                              hipStream_t stream)
{
    const float* feats = (const float*)d_in[0];
    const float* frw0 = (const float*)d_in[1];  const float* frb0 = (const float*)d_in[2];
    const float* frw1 = (const float*)d_in[3];  const float* frb1 = (const float*)d_in[4];
    const float* frhw = (const float*)d_in[5];  const float* frhb = (const float*)d_in[6];
    const float* fcw0 = (const float*)d_in[7];  const float* fcb0 = (const float*)d_in[8];
    const float* fcw1 = (const float*)d_in[9];  const float* fcb1 = (const float*)d_in[10];
    const float* fchw = (const float*)d_in[11]; const float* fchb = (const float*)d_in[12];
    const float* alw  = (const float*)d_in[13]; const float* alb  = (const float*)d_in[14];
    const float* orw  = (const float*)d_in[15]; const float* orb  = (const float*)d_in[16];
    const float* drw0 = (const float*)d_in[17]; const float* drb0 = (const float*)d_in[18];
    const float* drw1 = (const float*)d_in[19]; const float* drb1 = (const float*)d_in[20];
    const float* drhw = (const float*)d_in[21]; const float* drhb = (const float*)d_in[22];
    const float* dcw0 = (const float*)d_in[23]; const float* dcb0 = (const float*)d_in[24];
    const float* dcw1 = (const float*)d_in[25]; const float* dcb1 = (const float*)d_in[26];
    const float* dchw = (const float*)d_in[27]; const float* dchb = (const float*)d_in[28];
    const int*  stride_p = (const int*)d_in[29];

    float* out = (float*)d_out;   // fp32 output (proven round 8/9)
    float* o_fam_cls  = out;
    float* o_fam_bbox = out + 245760;
    float* o_odm_cls  = out + 327680;
    float* o_odm_bbox = out + 573440;
    float* o_anchors  = out + 655360;
    float* o_refine   = out + 737280;

    dim3 blk(256);

    const size_t NEED_FAST = 27395072;  // xt+T0+T1+P+WB+BB
    const size_t NEED_V9   = 8912896;

    if (ws_size >= NEED_FAST) {
        char* ws = (char*)d_ws;
        short* xt = (short*)(ws + 0);          // [16384][256] bf16
        short* T0 = (short*)(ws + 8388608);
        short* T1 = (short*)(ws + 16777216);
        short* P  = (short*)(ws + 25165824);   // [16384][32]
        short* WB = (short*)(ws + 26214400);   // [9][256][256] bf16 max
        float* BB = (float*)(ws + 27394048);   // [256] fp32

        dim3 gc(256, 4), gh(256, 1);

        v10_transpose<<<dim3(512, 8), blk, 0, stream>>>(feats, xt);

#define PREP(W, B, COUT, CIN, OCP, MODE) \
        v10_prep<<<dim3((9 * (OCP) * (CIN) + 255) / 256), blk, 0, stream>>>( \
            W, B, WB, BB, COUT, CIN, OCP, MODE)

        // FAM reg
        PREP(frw0, frb0, 256, 256, 256, 0);
        v10_conv<1, 0, 0, 256><<<gc, blk, 0, stream>>>(xt, WB, BB, T0, 256);
        PREP(frw1, frb1, 256, 256, 256, 0);
        v10_conv<1, 0, 0, 256><<<gc, blk, 0, stream>>>(T0, WB, BB, T1, 256);
        PREP(frhw, frhb, 5, 256, 64, 2);
        v10_conv<0, 1, 1, 256><<<gh, blk, 0, stream>>>(T1, WB, BB, o_fam_bbox, 5);
        // FAM cls
        PREP(fcw0, fcb0, 256, 256, 256, 0);
        v10_conv<1, 0, 0, 256><<<gc, blk, 0, stream>>>(xt, WB, BB, T0, 256);
        PREP(fcw1, fcb1, 256, 256, 256, 0);
        v10_conv<1, 0, 0, 256><<<gc, blk, 0, stream>>>(T0, WB, BB, T1, 256);
        PREP(fchw, fchb, 15, 256, 64, 2);
        v10_conv<0, 1, 1, 256><<<gh, blk, 0, stream>>>(T1, WB, BB, o_fam_cls, 15);
        // decode
        v9_decode<<<dim3(64), blk, 0, stream>>>(o_fam_bbox, o_anchors, o_refine, stride_p);
        // align conv -> T0
        PREP(alw, alb, 256, 256, 256, 0);
        v10_align<<<dim3(128, 4), blk, 0, stream>>>(xt, o_fam_bbox, WB, BB, stride_p, T0);
        // OR conv (rotation folded into prep) -> T1, no relu
        PREP(orw, orb, 256, 256, 256, 1);
        v10_conv<0, 0, 0, 256><<<gc, blk, 0, stream>>>(T0, WB, BB, T1, 256);
        // pool -> P
        v10_pool<<<dim3(2048), blk, 0, stream>>>(T1, P);
        // ODM reg: T1 -> T0 -> T1 -> head
        PREP(drw0, drb0, 256, 256, 256, 0);
        v10_conv<1, 0, 0, 256><<<gc, blk, 0, stream>>>(T1, WB, BB, T0, 256);
        PREP(drw1, drb1, 256, 256, 256, 0);
        v10_conv<1, 0, 0, 256><<<gc, blk, 0, stream>>>(T0, WB, BB, T1, 256);
        PREP(drhw, drhb, 5, 256, 64, 0);
        v10_conv<0, 1, 0, 256><<<gh, blk, 0, stream>>>(T1, WB, BB, o_odm_bbox, 5);
        // ODM cls: P -> T0 (Cin=32) -> T1 -> head
        PREP(dcw0, dcb0, 256, 32, 256, 0);
        v10_conv<1, 0, 0, 32><<<gc, blk, 0, stream>>>(P, WB, BB, T0, 256);
        PREP(dcw1, dcb1, 256, 256, 256, 0);
        v10_conv<1, 0, 0, 256><<<gc, blk, 0, stream>>>(T0, WB, BB, T1, 256);
        PREP(dchw, dchb, 15, 256, 64, 0);
        v10_conv<0, 1, 0, 256><<<gh, blk, 0, stream>>>(T1, WB, BB, o_odm_cls, 15);
#undef PREP
    } else if (ws_size >= NEED_V9) {
        // -------- verbatim round-9 passing path --------
        F8* A = (F8*)d_ws;
        F8* B = (F8*)((char*)d_ws + 4194304);
        F8* P = (F8*)((char*)d_ws + 8388608);
        dim3 gconv(128, 4);

        v9_conv3x3<float, 1, 0><<<gconv, blk, 0, stream>>>(feats, frw0, frb0, A, 256);
        v9_conv3x3<F8,    1, 0><<<gconv, blk, 0, stream>>>(A, frw1, frb1, B, 256);
        v9_head1x1<<<dim3(5 * 64), blk, 0, stream>>>(B, frhw, frhb, o_fam_bbox, 5);
        v9_conv3x3<float, 1, 0><<<gconv, blk, 0, stream>>>(feats, fcw0, fcb0, A, 256);
        v9_conv3x3<F8,    1, 0><<<gconv, blk, 0, stream>>>(A, fcw1, fcb1, B, 256);
        v9_head1x1<<<dim3(15 * 64), blk, 0, stream>>>(B, fchw, fchb, o_fam_cls, 15);
        v9_decode<<<dim3(64), blk, 0, stream>>>(o_fam_bbox, o_anchors, o_refine, stride_p);
        v9_align<<<gconv, blk, 0, stream>>>(feats, o_fam_bbox, alw, alb, stride_p, A);
        v9_conv3x3<F8, 0, 1><<<gconv, blk, 0, stream>>>(A, orw, orb, B, 256);
        v9_pool<<<dim3(2048), blk, 0, stream>>>(B, P);
        v9_conv3x3<F8, 1, 0><<<gconv, blk, 0, stream>>>(B, drw0, drb0, A, 256);
        v9_conv3x3<F8, 1, 0><<<gconv, blk, 0, stream>>>(A, drw1, drb1, B, 256);
        v9_head3x3<<<dim3(5 * 64), blk, 0, stream>>>(B, drhw, drhb, o_odm_bbox, 5);
        v9_conv3x3<F8, 1, 0><<<gconv, blk, 0, stream>>>(P, dcw0, dcb0, A, 32);
        v9_conv3x3<F8, 1, 0><<<gconv, blk, 0, stream>>>(A, dcw1, dcb1, B, 256);
        v9_head3x3<<<dim3(15 * 64), blk, 0, stream>>>(B, dchw, dchb, o_odm_cls, 15);
    }
}

// Round 11
// 715.911 us; speedup vs baseline: 7.0511x; 3.1071x over previous
//
#include <hip/hip_runtime.h>
#include <hip/hip_bf16.h>
#include <hip/hip_fp16.h>

#define HW 128
#define NPX 16384
#define CC 256

typedef short  bf16x8  __attribute__((ext_vector_type(8)));
typedef short  short4v __attribute__((ext_vector_type(4)));
typedef float  f32x4   __attribute__((ext_vector_type(4)));

// ---- scalar bf16 bit helpers (RNE) ----
static __device__ __forceinline__ short f2bs(float v) {
    union { float f; unsigned u; } x; x.f = v;
    unsigned r = x.u + 0x7FFFu + ((x.u >> 16) & 1u);
    return (short)(r >> 16);
}
static __device__ __forceinline__ float bs2f(short s) {
    union { unsigned u; float f; } x; x.u = ((unsigned)(unsigned short)s) << 16;
    return x.f;
}

// fp8 e5m2 (v9 fallback path)
struct F8 { unsigned char b; };
__device__ __forceinline__ unsigned char enc8(float v) {
    unsigned short u = __half_as_ushort(__float2half(v));
    unsigned short s = u & 0x8000, mag = u & 0x7FFF;
    mag = (unsigned short)(mag + 0x0080);
    return (unsigned char)((unsigned short)(s | mag) >> 8);
}
__device__ __forceinline__ float dec8(F8 v) {
    return __half2float(__ushort_as_half((unsigned short)(v.b) << 8));
}
__device__ __forceinline__ float ldg_(const float* p) { return *p; }
__device__ __forceinline__ float ldg_(const F8* p)    { return dec8(*p); }

// ORConv rotation: c_ROT[r][k] = RING[(INV[k]-r)&7], RING={0,1,2,5,8,7,6,3}.
__constant__ int c_ROT9[8][9] = {
    {0,1,2,3,4,5,6,7,8},
    {3,0,1,6,4,2,7,8,5},
    {6,3,0,7,4,1,8,5,2},
    {7,6,3,8,4,0,5,2,1},
    {8,7,6,5,4,3,2,1,0},
    {5,8,7,2,4,6,1,0,3},
    {2,5,8,1,4,7,0,3,6},
    {1,2,5,0,4,8,3,6,7},
};

// decode helper: fam_bbox fp32 [5,NPX] + px -> refined rotated box (fp32)
__device__ __forceinline__ void v9_decode_px(
    const float* bbox, int px, float s,
    float& gx, float& gy, float& gw, float& gh, float& ga)
{
    int y = px >> 7, x = px & 127;
    float ax = x * s + 3.5f, ay = y * s + 3.5f;
    float dx = bbox[0 * NPX + px];
    float dy = bbox[1 * NPX + px];
    float dw = bbox[2 * NPX + px];
    float dh = bbox[3 * NPX + px];
    float dt = bbox[4 * NPX + px];
    const float maxr = 13.815510558f;
    dw = fminf(fmaxf(dw, -maxr), maxr);
    dh = fminf(fmaxf(dh, -maxr), maxr);
    gx = dx * 32.f + ax;
    gy = dy * 32.f + ay;
    gw = 32.f * expf(dw);
    gh = 32.f * expf(dh);
    const float PI = 3.14159265358979323846f;
    float m = fmodf(dt + PI * 0.25f, PI);
    if (m < 0.f) m += PI;
    ga = m - PI * 0.25f;
}

// ===========================================================================
// ============================  V11 FAST PATH  ==============================
// Activations in [px][ci] bf16. MFMA 16x16x32 bf16 implicit-GEMM convs with
// LDS-staged input tiles (v11_conv). Other kernels carried from v10.
// ===========================================================================

// feats [256][16384] fp32 -> xt [16384][256] bf16 (LDS 32x32 tile transpose)
__global__ __launch_bounds__(256) void v10_transpose(
    const float* __restrict__ f, short* __restrict__ xt)
{
    __shared__ float tile[32][33];
    int px0 = blockIdx.x * 32, ci0 = blockIdx.y * 32;
    int tx = threadIdx.x & 31, ty = threadIdx.x >> 5;
#pragma unroll
    for (int i = 0; i < 4; ++i) {
        int ci = ty + i * 8;
        tile[ci][tx] = f[(size_t)(ci0 + ci) * NPX + px0 + tx];
    }
    __syncthreads();
#pragma unroll
    for (int i = 0; i < 4; ++i) {
        int pxr = ty + i * 8;
        xt[(size_t)(px0 + pxr) * 256 + ci0 + tx] = f2bs(tile[tx][pxr]);
    }
}

// weight prep -> wb[t][ocp][ci] bf16 (+ padded bias bb[ocp] fp32)
__global__ __launch_bounds__(256) void v10_prep(
    const float* __restrict__ w, const float* __restrict__ bias,
    short* __restrict__ wb, float* __restrict__ bb,
    int Cout, int Cin, int OCP, int mode)
{
    int g = blockIdx.x * 256 + threadIdx.x;
    if (g < OCP) bb[g] = (g < Cout) ? ((mode == 1) ? bias[g >> 3] : bias[g]) : 0.f;
    int tot = 9 * OCP * Cin;
    if (g >= tot) return;
    int t   = g / (OCP * Cin);
    int rem = g - t * OCP * Cin;
    int oc  = rem / Cin;
    int ci  = rem - oc * Cin;
    float v = 0.f;
    if (oc < Cout) {
        if (mode == 0)      v = w[((size_t)oc * Cin + ci) * 9 + t];
        else if (mode == 1) { int o = oc >> 3, r = oc & 7;
                              v = w[((size_t)o * Cin + ci) * 9 + c_ROT9[r][t]]; }
        else if (t == 4)    v = w[(size_t)oc * Cin + ci];
    }
    wb[g] = f2bs(v);
}

// MFMA conv with LDS-staged input tile.
// in [px][CIN] bf16, wb [t][OCP][CIN] bf16.
// HEAD=0: out [px][256] bf16 (+bias, opt relu). HEAD=1: out fp32 [oc][NPX].
// Grid (256, OCP/64): blockIdx.x = (row<<1)|xhalf. Block 256 = 4 waves.
template <int RELU, int HEAD, int ONLY1, int CIN>
__global__ __launch_bounds__(256) void v11_conv(
    const short* __restrict__ xin, const short* __restrict__ wb,
    const float* __restrict__ bb, void* __restrict__ outv, int CoutAct)
{
    const int OCP  = gridDim.y * 64;
    const int y    = blockIdx.x >> 1;
    const int xh   = (blockIdx.x & 1) * 64;
    const int ocb  = blockIdx.y * 64;
    const int tid  = threadIdx.x;
    const int wv   = tid >> 6;
    const int lane = tid & 63;
    const int quad = lane >> 4;
    const int l15  = lane & 15;
    const int ocw  = ocb + wv * 16;

    // LDS tile: rows r=0..2 (image y-1+r), cols c=0..65 (image xh-1+c),
    // ci-slice of 32. Row stride 40 shorts (80 B, 16B-aligned; <=2-way banks).
    __shared__ short S[3 * 66 * 40];

    f32x4 acc[4];
#pragma unroll
    for (int p = 0; p < 4; ++p) acc[p] = (f32x4){0.f, 0.f, 0.f, 0.f};
    const bf16x8 zf = (bf16x8){0, 0, 0, 0, 0, 0, 0, 0};

    for (int cib = 0; cib < CIN; cib += 32) {
        __syncthreads();
        // stage 3*66 positions x 32 ci (as 4x 16B chunks) with zero halo
        for (int e = tid; e < 792; e += 256) {
            int pos = e >> 2, part = e & 3;
            int r = pos / 66, c = pos - r * 66;
            int yy = y - 1 + r, xx = xh - 1 + c;
            bf16x8 v = zf;
            if (yy >= 0 && yy < HW && xx >= 0 && xx < HW)
                v = *(const bf16x8*)(xin +
                    ((size_t)(yy * HW + xx) * CIN + cib + part * 8));
            *(bf16x8*)(&S[(r * 66 + c) * 40 + part * 8]) = v;
        }
        __syncthreads();

        // prefetch A fragments (weights) for all taps of this ci-slice
        bf16x8 a[9];
#pragma unroll
        for (int t = (ONLY1 ? 4 : 0); t < (ONLY1 ? 5 : 9); ++t)
            a[t] = *(const bf16x8*)(wb +
                ((size_t)(t * OCP + ocw + l15) * CIN + cib + quad * 8));

#pragma unroll
        for (int t = (ONLY1 ? 4 : 0); t < (ONLY1 ? 5 : 9); ++t) {
            const int r = t / 3, dxk = t % 3 - 1;
#pragma unroll
            for (int p = 0; p < 4; ++p) {
                int c = 1 + p * 16 + l15 + dxk;
                bf16x8 b = *(const bf16x8*)(&S[(r * 66 + c) * 40 + quad * 8]);
                acc[p] = __builtin_amdgcn_mfma_f32_16x16x32_bf16(a[t], b, acc[p], 0, 0, 0);
            }
        }
    }

#pragma unroll
    for (int p = 0; p < 4; ++p) {
        const int px  = y * HW + xh + p * 16 + l15;
        const int ocq = ocw + quad * 4;
        if (HEAD) {
            float* o = (float*)outv;
#pragma unroll
            for (int r = 0; r < 4; ++r)
                if (ocq + r < CoutAct)
                    o[(size_t)(ocq + r) * NPX + px] = acc[p][r] + bb[ocq + r];
        } else {
            short4v s4;
#pragma unroll
            for (int r = 0; r < 4; ++r) {
                float v = acc[p][r] + bb[ocq + r];
                if (RELU) v = fmaxf(v, 0.f);
                s4[r] = f2bs(v);
            }
            *(short4v*)((short*)outv + (size_t)px * 256 + ocq) = s4;
        }
    }
}

// MFMA align conv (unchanged from passing v10)
__global__ __launch_bounds__(256) void v10_align(
    const short* __restrict__ xt, const float* __restrict__ bbox,
    const short* __restrict__ wb, const float* __restrict__ bb,
    const int* __restrict__ stride_p, short* __restrict__ outa)
{
    const int y    = blockIdx.x;
    const int ocb  = blockIdx.y * 64;
    const int tid  = threadIdx.x;
    const int wv   = tid >> 6, lane = tid & 63, quad = lane >> 4, l15 = lane & 15;
    const int ocw  = ocb + wv * 16;

    __shared__ int   s_ix[1152], s_iy[1152];
    __shared__ float s_w00[1152], s_w01[1152], s_w10[1152], s_w11[1152];
    __shared__ short S[128][40];

    const float s = (float)(*stride_p);
    for (int e = tid; e < 1152; e += 256) {
        int k = e >> 7, xx = e & 127;
        int px = y * HW + xx;
        float gx, gy, gw, gh, ga;
        v9_decode_px(bbox, px, s, gx, gy, gw, gh, ga);
        float axc = gx / s, ayc = gy / s;
        float aw3 = gw / (3.f * s), ah3 = gh / (3.f * s);
        float cs = cosf(ga), sn = sinf(ga);
        float kx = (float)(k % 3 - 1), ky = (float)(k / 3 - 1);
        float ddx = aw3 * kx, ddy = ah3 * ky;
        float xf = cs * ddx - sn * ddy + axc;
        float yf = sn * ddx + cs * ddy + ayc;
        float fx = floorf(xf), fy = floorf(yf);
        int ix = (int)fx, iy = (int)fy;
        float wx1 = xf - fx, wx0 = 1.f - wx1;
        float wy1 = yf - fy, wy0 = 1.f - wy1;
        bool x0v = (ix >= 0) && (ix < HW), x1v = (ix + 1 >= 0) && (ix + 1 < HW);
        bool y0v = (iy >= 0) && (iy < HW), y1v = (iy + 1 >= 0) && (iy + 1 < HW);
        s_ix[e] = ix; s_iy[e] = iy;
        s_w00[e] = (y0v && x0v) ? wy0 * wx0 : 0.f;
        s_w01[e] = (y0v && x1v) ? wy0 * wx1 : 0.f;
        s_w10[e] = (y1v && x0v) ? wy1 * wx0 : 0.f;
        s_w11[e] = (y1v && x1v) ? wy1 * wx1 : 0.f;
    }

    f32x4 acc[8];
#pragma unroll
    for (int p = 0; p < 8; ++p) acc[p] = (f32x4){0.f, 0.f, 0.f, 0.f};

    const int spx = tid >> 1;
    const int sci = (tid & 1) * 16;

    for (int cib = 0; cib < 256; cib += 32) {
        for (int t = 0; t < 9; ++t) {
            __syncthreads();
            {
                int e = t * 128 + spx;
                int ix = s_ix[e], iy = s_iy[e];
                float w00 = s_w00[e], w01 = s_w01[e], w10 = s_w10[e], w11 = s_w11[e];
                int x0c = min(max(ix, 0), HW - 1), x1c = min(max(ix + 1, 0), HW - 1);
                int y0c = min(max(iy, 0), HW - 1), y1c = min(max(iy + 1, 0), HW - 1);
                const short* p00 = xt + ((size_t)(y0c * HW + x0c) * 256 + cib + sci);
                const short* p01 = xt + ((size_t)(y0c * HW + x1c) * 256 + cib + sci);
                const short* p10 = xt + ((size_t)(y1c * HW + x0c) * 256 + cib + sci);
                const short* p11 = xt + ((size_t)(y1c * HW + x1c) * 256 + cib + sci);
                bf16x8 a0 = *(const bf16x8*)p00, a1 = *(const bf16x8*)(p00 + 8);
                bf16x8 b0 = *(const bf16x8*)p01, b1 = *(const bf16x8*)(p01 + 8);
                bf16x8 c0 = *(const bf16x8*)p10, c1 = *(const bf16x8*)(p10 + 8);
                bf16x8 d0 = *(const bf16x8*)p11, d1 = *(const bf16x8*)(p11 + 8);
#pragma unroll
                for (int i = 0; i < 8; ++i) {
                    float v = w00 * bs2f(a0[i]) + w01 * bs2f(b0[i])
                            + w10 * bs2f(c0[i]) + w11 * bs2f(d0[i]);
                    S[spx][sci + i] = f2bs(v);
                }
#pragma unroll
                for (int i = 0; i < 8; ++i) {
                    float v = w00 * bs2f(a1[i]) + w01 * bs2f(b1[i])
                            + w10 * bs2f(c1[i]) + w11 * bs2f(d1[i]);
                    S[spx][sci + 8 + i] = f2bs(v);
                }
            }
            __syncthreads();
            bf16x8 a = *(const bf16x8*)(wb +
                ((size_t)(t * 256 + ocw + l15) * 256 + cib + quad * 8));
#pragma unroll
            for (int p = 0; p < 8; ++p) {
                bf16x8 b = *(const bf16x8*)(&S[p * 16 + l15][quad * 8]);
                acc[p] = __builtin_amdgcn_mfma_f32_16x16x32_bf16(a, b, acc[p], 0, 0, 0);
            }
        }
    }
#pragma unroll
    for (int p = 0; p < 8; ++p) {
        const int px  = y * HW + p * 16 + l15;
        const int ocq = ocw + quad * 4;
        short4v s4;
#pragma unroll
        for (int r = 0; r < 4; ++r)
            s4[r] = f2bs(fmaxf(acc[p][r] + bb[ocq + r], 0.f));
        *(short4v*)(outa + (size_t)px * 256 + ocq) = s4;
    }
}

// pool: T [px][256] bf16 -> P [px][32] bf16 (max over 8 consecutive oc)
__global__ __launch_bounds__(256) void v10_pool(
    const short* __restrict__ t1, short* __restrict__ p)
{
    int g = blockIdx.x * 256 + threadIdx.x;
    if (g >= 32 * NPX) return;
    int px = g >> 5, c = g & 31;
    const short* q = t1 + (size_t)px * 256 + c * 8;
    float m = bs2f(q[0]);
#pragma unroll
    for (int r = 1; r < 8; ++r) m = fmaxf(m, bs2f(q[r]));
    p[(size_t)px * 32 + c] = f2bs(m);
}

// anchors + refine decode -> fp32 d_out (shared by both paths)
__global__ __launch_bounds__(256) void v9_decode(
    const float* __restrict__ bbox, float* __restrict__ anchors_out,
    float* __restrict__ refine_out, const int* __restrict__ stride_p)
{
    int px = blockIdx.x * 256 + threadIdx.x;
    if (px >= NPX) return;
    float s = (float)(*stride_p);
    int y = px >> 7, x = px & 127;
    anchors_out[px * 5 + 0] = x * s + 3.5f;
    anchors_out[px * 5 + 1] = y * s + 3.5f;
    anchors_out[px * 5 + 2] = 32.f;
    anchors_out[px * 5 + 3] = 32.f;
    anchors_out[px * 5 + 4] = 0.f;
    float gx, gy, gw, gh, ga;
    v9_decode_px(bbox, px, s, gx, gy, gw, gh, ga);
    refine_out[px * 5 + 0] = gx;
    refine_out[px * 5 + 1] = gy;
    refine_out[px * 5 + 2] = gw;
    refine_out[px * 5 + 3] = gh;
    refine_out[px * 5 + 4] = ga;
}

// ===========================================================================
// ============  V9 FALLBACK (verbatim from passing round 9)  ================
// ===========================================================================
template <typename TIN, int RELU, int ORCONV>
__global__ __launch_bounds__(256) void v9_conv3x3(
    const TIN* __restrict__ in, const float* __restrict__ w,
    const float* __restrict__ bias, F8* __restrict__ out, int Cin)
{
    const int y   = blockIdx.x;
    const int ocb = blockIdx.y * 64;
    const int tid = threadIdx.x;
    const int xg  = tid & 15;
    const int og  = tid >> 4;
    const int x0  = xg * 8;
    const int oc0 = ocb + og * 4;

    __shared__ float srow[3][132];
    float acc[4][8];
#pragma unroll
    for (int i = 0; i < 4; ++i)
#pragma unroll
        for (int j = 0; j < 8; ++j) acc[i][j] = 0.f;

    for (int ci = 0; ci < Cin; ++ci) {
        __syncthreads();
        const TIN* inp = in + (size_t)ci * NPX;
        for (int t = tid; t < 3 * 130; t += 256) {
            int r = t / 130, c = t - r * 130;
            int yy = y - 1 + r, xx = c - 1;
            float v = 0.f;
            if (yy >= 0 && yy < HW && xx >= 0 && xx < HW) v = ldg_(inp + yy * HW + xx);
            srow[r][c] = v;
        }
        __syncthreads();
        float wv[4][9];
#pragma unroll
        for (int i = 0; i < 4; ++i) {
            if (ORCONV) {
                int oc = oc0 + i;
                const float* wp = w + ((size_t)(oc >> 3) * Cin + ci) * 9;
                const int* rot = c_ROT9[oc & 7];
#pragma unroll
                for (int k = 0; k < 9; ++k) wv[i][k] = wp[rot[k]];
            } else {
                const float* wp = w + ((size_t)(oc0 + i) * Cin + ci) * 9;
#pragma unroll
                for (int k = 0; k < 9; ++k) wv[i][k] = wp[k];
            }
        }
#pragma unroll
        for (int r = 0; r < 3; ++r) {
            float iv[10];
#pragma unroll
            for (int c = 0; c < 10; ++c) iv[c] = srow[r][x0 + c];
#pragma unroll
            for (int dxk = 0; dxk < 3; ++dxk)
#pragma unroll
                for (int i = 0; i < 4; ++i)
#pragma unroll
                    for (int j = 0; j < 8; ++j)
                        acc[i][j] += iv[j + dxk] * wv[i][r * 3 + dxk];
        }
    }
#pragma unroll
    for (int i = 0; i < 4; ++i) {
        float b = ORCONV ? bias[(oc0 + i) >> 3] : bias[oc0 + i];
#pragma unroll
        for (int j = 0; j < 8; ++j) {
            float v = acc[i][j] + b;
            if (RELU) v = fmaxf(v, 0.f);
            out[(size_t)(oc0 + i) * NPX + y * HW + x0 + j].b = enc8(v);
        }
    }
}

__global__ __launch_bounds__(256) void v9_head1x1(
    const F8* __restrict__ in, const float* __restrict__ w,
    const float* __restrict__ bias, float* __restrict__ out, int Cout)
{
    int g = blockIdx.x * 256 + threadIdx.x;
    if (g >= Cout * NPX) return;
    int px = g & (NPX - 1);
    int oc = g >> 14;
    float acc = bias[oc];
    const float* wp = w + (size_t)oc * CC;
    for (int ci = 0; ci < CC; ++ci)
        acc += dec8(in[(size_t)ci * NPX + px]) * wp[ci];
    out[g] = acc;
}

__global__ __launch_bounds__(256) void v9_head3x3(
    const F8* __restrict__ in, const float* __restrict__ w,
    const float* __restrict__ bias, float* __restrict__ out, int Cout)
{
    int g = blockIdx.x * 256 + threadIdx.x;
    if (g >= Cout * NPX) return;
    int px = g & (NPX - 1);
    int oc = g >> 14;
    int y = px >> 7, x = px & 127;
    float acc = bias[oc];
    for (int ci = 0; ci < CC; ++ci) {
        const F8* ip = in + (size_t)ci * NPX;
        const float* wp = w + ((size_t)oc * CC + ci) * 9;
#pragma unroll
        for (int dy = 0; dy < 3; ++dy) {
            int yy = y + dy - 1;
            if (yy < 0 || yy >= HW) continue;
#pragma unroll
            for (int dxk = 0; dxk < 3; ++dxk) {
                int xx = x + dxk - 1;
                if (xx < 0 || xx >= HW) continue;
                acc += dec8(ip[yy * HW + xx]) * wp[dy * 3 + dxk];
            }
        }
    }
    out[g] = acc;
}

__global__ __launch_bounds__(256) void v9_align(
    const float* __restrict__ in, const float* __restrict__ bbox,
    const float* __restrict__ w, const float* __restrict__ bias,
    const int* __restrict__ stride_p, F8* __restrict__ out)
{
    const int y   = blockIdx.x;
    const int ocb = blockIdx.y * 64;
    const int tid = threadIdx.x;
    const int xg  = tid & 15;
    const int og  = tid >> 4;
    const int x0  = xg * 8;
    const int oc0 = ocb + og * 4;

    __shared__ float smp[9][128];
    __shared__ int   s_ix[1152], s_iy[1152];
    __shared__ float s_wx1[1152], s_wy1[1152];

    const float s = (float)(*stride_p);
    for (int t = tid; t < 1152; t += 256) {
        int k = t >> 7, xx = t & 127;
        int px = y * HW + xx;
        float gx, gy, gw, gh, ga;
        v9_decode_px(bbox, px, s, gx, gy, gw, gh, ga);
        float axc = gx / s, ayc = gy / s;
        float aw3 = gw / (s * 3.f), ah3 = gh / (s * 3.f);
        float cs = cosf(ga), sn = sinf(ga);
        float kx = (float)(k % 3 - 1), ky = (float)(k / 3 - 1);
        float ddx = aw3 * kx, ddy = ah3 * ky;
        float xf = cs * ddx - sn * ddy + axc;
        float yf = sn * ddx + cs * ddy + ayc;
        float fx = floorf(xf), fy = floorf(yf);
        s_ix[t]  = (int)fx;
        s_iy[t]  = (int)fy;
        s_wx1[t] = xf - fx;
        s_wy1[t] = yf - fy;
    }

    float acc[4][8];
#pragma unroll
    for (int i = 0; i < 4; ++i)
#pragma unroll
        for (int j = 0; j < 8; ++j) acc[i][j] = 0.f;

    for (int ci = 0; ci < CC; ++ci) {
        __syncthreads();
        const float* ip = in + (size_t)ci * NPX;
        for (int t = tid; t < 1152; t += 256) {
            int ix = s_ix[t], iy = s_iy[t];
            float wx1 = s_wx1[t], wx0 = 1.f - wx1;
            float wy1 = s_wy1[t], wy0 = 1.f - wy1;
            float v = 0.f;
            bool xv0 = (ix >= 0) && (ix < HW);
            bool xv1 = (ix + 1 >= 0) && (ix + 1 < HW);
            bool yv0 = (iy >= 0) && (iy < HW);
            bool yv1 = (iy + 1 >= 0) && (iy + 1 < HW);
            if (yv0 && xv0) v += ip[iy * HW + ix] * wy0 * wx0;
            if (yv0 && xv1) v += ip[iy * HW + ix + 1] * wy0 * wx1;
            if (yv1 && xv0) v += ip[(iy + 1) * HW + ix] * wy1 * wx0;
            if (yv1 && xv1) v += ip[(iy + 1) * HW + ix + 1] * wy1 * wx1;
            smp[t >> 7][t & 127] = v;
        }
        __syncthreads();

        float wv[4][9];
#pragma unroll
        for (int i = 0; i < 4; ++i) {
            const float* wp = w + ((size_t)(oc0 + i) * CC + ci) * 9;
#pragma unroll
            for (int k = 0; k < 9; ++k) wv[i][k] = wp[k];
        }
#pragma unroll
        for (int k = 0; k < 9; ++k) {
            float iv[8];
#pragma unroll
            for (int j = 0; j < 8; ++j) iv[j] = smp[k][x0 + j];
#pragma unroll
            for (int i = 0; i < 4; ++i)
#pragma unroll
                for (int j = 0; j < 8; ++j)
                    acc[i][j] += iv[j] * wv[i][k];
        }
    }
#pragma unroll
    for (int i = 0; i < 4; ++i) {
        float b = bias[oc0 + i];
#pragma unroll
        for (int j = 0; j < 8; ++j)
            out[(size_t)(oc0 + i) * NPX + y * HW + x0 + j].b =
                enc8(fmaxf(acc[i][j] + b, 0.f));
    }
}

__global__ __launch_bounds__(256) void v9_pool(
    const F8* __restrict__ orf, F8* __restrict__ pooled)
{
    int g = blockIdx.x * 256 + threadIdx.x;
    if (g >= 32 * NPX) return;
    int px = g & (NPX - 1);
    int c  = g >> 14;
    float m = -3.4e38f;
#pragma unroll
    for (int r = 0; r < 8; ++r)
        m = fmaxf(m, dec8(orf[(size_t)(c * 8 + r) * NPX + px]));
    pooled[g].b = enc8(m);
}

// ===========================================================================
extern "C" void kernel_launch(void* const* d_in, const int* in_sizes, int n_in,
                              void* d_out, int out_size, void* d_ws, size_t ws_size,
                              hipStream_t stream)
{
    const float* feats = (const float*)d_in[0];
    const float* frw0 = (const float*)d_in[1];  const float* frb0 = (const float*)d_in[2];
    const float* frw1 = (const float*)d_in[3];  const float* frb1 = (const float*)d_in[4];
    const float* frhw = (const float*)d_in[5];  const float* frhb = (const float*)d_in[6];
    const float* fcw0 = (const float*)d_in[7];  const float* fcb0 = (const float*)d_in[8];
    const float* fcw1 = (const float*)d_in[9];  const float* fcb1 = (const float*)d_in[10];
    const float* fchw = (const float*)d_in[11]; const float* fchb = (const float*)d_in[12];
    const float* alw  = (const float*)d_in[13]; const float* alb  = (const float*)d_in[14];
    const float* orw  = (const float*)d_in[15]; const float* orb  = (const float*)d_in[16];
    const float* drw0 = (const float*)d_in[17]; const float* drb0 = (const float*)d_in[18];
    const float* drw1 = (const float*)d_in[19]; const float* drb1 = (const float*)d_in[20];
    const float* drhw = (const float*)d_in[21]; const float* drhb = (const float*)d_in[22];
    const float* dcw0 = (const float*)d_in[23]; const float* dcb0 = (const float*)d_in[24];
    const float* dcw1 = (const float*)d_in[25]; const float* dcb1 = (const float*)d_in[26];
    const float* dchw = (const float*)d_in[27]; const float* dchb = (const float*)d_in[28];
    const int*  stride_p = (const int*)d_in[29];

    float* out = (float*)d_out;   // fp32 output (proven round 8/9)
    float* o_fam_cls  = out;
    float* o_fam_bbox = out + 245760;
    float* o_odm_cls  = out + 327680;
    float* o_odm_bbox = out + 573440;
    float* o_anchors  = out + 655360;
    float* o_refine   = out + 737280;

    dim3 blk(256);

    const size_t NEED_FAST = 27395072;
    const size_t NEED_V9   = 8912896;

    if (ws_size >= NEED_FAST) {
        char* ws = (char*)d_ws;
        short* xt = (short*)(ws + 0);          // [16384][256] bf16
        short* T0 = (short*)(ws + 8388608);
        short* T1 = (short*)(ws + 16777216);
        short* P  = (short*)(ws + 25165824);   // [16384][32]
        short* WB = (short*)(ws + 26214400);   // [9][256][256] bf16 max
        float* BB = (float*)(ws + 27394048);   // [256] fp32

        dim3 gc(256, 4), gh(256, 1);

        v10_transpose<<<dim3(512, 8), blk, 0, stream>>>(feats, xt);

#define PREP(W, B, COUT, CIN, OCP, MODE) \
        v10_prep<<<dim3((9 * (OCP) * (CIN) + 255) / 256), blk, 0, stream>>>( \
            W, B, WB, BB, COUT, CIN, OCP, MODE)

        // FAM reg
        PREP(frw0, frb0, 256, 256, 256, 0);
        v11_conv<1, 0, 0, 256><<<gc, blk, 0, stream>>>(xt, WB, BB, T0, 256);
        PREP(frw1, frb1, 256, 256, 256, 0);
        v11_conv<1, 0, 0, 256><<<gc, blk, 0, stream>>>(T0, WB, BB, T1, 256);
        PREP(frhw, frhb, 5, 256, 64, 2);
        v11_conv<0, 1, 1, 256><<<gh, blk, 0, stream>>>(T1, WB, BB, o_fam_bbox, 5);
        // FAM cls
        PREP(fcw0, fcb0, 256, 256, 256, 0);
        v11_conv<1, 0, 0, 256><<<gc, blk, 0, stream>>>(xt, WB, BB, T0, 256);
        PREP(fcw1, fcb1, 256, 256, 256, 0);
        v11_conv<1, 0, 0, 256><<<gc, blk, 0, stream>>>(T0, WB, BB, T1, 256);
        PREP(fchw, fchb, 15, 256, 64, 2);
        v11_conv<0, 1, 1, 256><<<gh, blk, 0, stream>>>(T1, WB, BB, o_fam_cls, 15);
        // decode
        v9_decode<<<dim3(64), blk, 0, stream>>>(o_fam_bbox, o_anchors, o_refine, stride_p);
        // align conv -> T0
        PREP(alw, alb, 256, 256, 256, 0);
        v10_align<<<dim3(128, 4), blk, 0, stream>>>(xt, o_fam_bbox, WB, BB, stride_p, T0);
        // OR conv (rotation folded into prep) -> T1, no relu
        PREP(orw, orb, 256, 256, 256, 1);
        v11_conv<0, 0, 0, 256><<<gc, blk, 0, stream>>>(T0, WB, BB, T1, 256);
        // pool -> P
        v10_pool<<<dim3(2048), blk, 0, stream>>>(T1, P);
        // ODM reg: T1 -> T0 -> T1 -> head
        PREP(drw0, drb0, 256, 256, 256, 0);
        v11_conv<1, 0, 0, 256><<<gc, blk, 0, stream>>>(T1, WB, BB, T0, 256);
        PREP(drw1, drb1, 256, 256, 256, 0);
        v11_conv<1, 0, 0, 256><<<gc, blk, 0, stream>>>(T0, WB, BB, T1, 256);
        PREP(drhw, drhb, 5, 256, 64, 0);
        v11_conv<0, 1, 0, 256><<<gh, blk, 0, stream>>>(T1, WB, BB, o_odm_bbox, 5);
        // ODM cls: P -> T0 (Cin=32) -> T1 -> head
        PREP(dcw0, dcb0, 256, 32, 256, 0);
        v11_conv<1, 0, 0, 32><<<gc, blk, 0, stream>>>(P, WB, BB, T0, 256);
        PREP(dcw1, dcb1, 256, 256, 256, 0);
        v11_conv<1, 0, 0, 256><<<gc, blk, 0, stream>>>(T0, WB, BB, T1, 256);
        PREP(dchw, dchb, 15, 256, 64, 0);
        v11_conv<0, 1, 0, 256><<<gh, blk, 0, stream>>>(T1, WB, BB, o_odm_cls, 15);
#undef PREP
    } else if (ws_size >= NEED_V9) {
        // -------- verbatim round-9 passing path --------
        F8* A = (F8*)d_ws;
        F8* B = (F8*)((char*)d_ws + 4194304);
        F8* P = (F8*)((char*)d_ws + 8388608);
        dim3 gconv(128, 4);

        v9_conv3x3<float, 1, 0><<<gconv, blk, 0, stream>>>(feats, frw0, frb0, A, 256);
        v9_conv3x3<F8,    1, 0><<<gconv, blk, 0, stream>>>(A, frw1, frb1, B, 256);
        v9_head1x1<<<dim3(5 * 64), blk, 0, stream>>>(B, frhw, frhb, o_fam_bbox, 5);
        v9_conv3x3<float, 1, 0><<<gconv, blk, 0, stream>>>(feats, fcw0, fcb0, A, 256);
        v9_conv3x3<F8,    1, 0><<<gconv, blk, 0, stream>>>(A, fcw1, fcb1, B, 256);
        v9_head1x1<<<dim3(15 * 64), blk, 0, stream>>>(B, fchw, fchb, o_fam_cls, 15);
        v9_decode<<<dim3(64), blk, 0, stream>>>(o_fam_bbox, o_anchors, o_refine, stride_p);
        v9_align<<<gconv, blk, 0, stream>>>(feats, o_fam_bbox, alw, alb, stride_p, A);
        v9_conv3x3<F8, 0, 1><<<gconv, blk, 0, stream>>>(A, orw, orb, B, 256);
        v9_pool<<<dim3(2048), blk, 0, stream>>>(B, P);
        v9_conv3x3<F8, 1, 0><<<gconv, blk, 0, stream>>>(B, drw0, drb0, A, 256);
        v9_conv3x3<F8, 1, 0><<<gconv, blk, 0, stream>>>(A, drw1, drb1, B, 256);
        v9_head3x3<<<dim3(5 * 64), blk, 0, stream>>>(B, drhw, drhb, o_odm_bbox, 5);
        v9_conv3x3<F8, 1, 0><<<gconv, blk, 0, stream>>>(P, dcw0, dcb0, A, 32);
        v9_conv3x3<F8, 1, 0><<<gconv, blk, 0, stream>>>(A, dcw1, dcb1, B, 256);
        v9_head3x3<<<dim3(15 * 64), blk, 0, stream>>>(B, dchw, dchb, o_odm_cls, 15);
    }
}